// Round 3
// baseline (539.031 us; speedup 1.0000x reference)
//
#include <hip/hip_runtime.h>
#include <hip/hip_bf16.h>

// B=2, S=128, H=12, DH=64, HID=768
// scores(b,h,i,j) = dot64(q+ra, k+rb)/8 + mask ; ra=ip[r,64c+d], rb=ip[r,768+64c+d]
//   t = h*16384 + i*128 + j ; r = t/12, c = t%12
//   ip = inference_path @ Wip  -- 77 GFLOP bf16-MFMA GEMM, never materialized.

typedef __attribute__((ext_vector_type(8))) __bf16 bf16x8;
typedef __attribute__((ext_vector_type(16))) float f32x16;

// ---------------- kernel A: q/k/v/pv projections (bf16 MFMA, 64x64 tiles) ----------------
// grid (37, 4): n0 = bx*64 in combined-col space [q|k|v|pv]=2368, m0 = by*64.
__global__ __launch_bounds__(256)
void proj_kernel(const float* __restrict__ hs,
                 const float* __restrict__ Wq, const float* __restrict__ bq,
                 const float* __restrict__ Wk, const float* __restrict__ bk,
                 const float* __restrict__ Wv, const float* __restrict__ bv,
                 const float* __restrict__ Wpv, const float* __restrict__ bpv,
                 float* __restrict__ qkv) {
  const int n0 = blockIdx.x * 64;
  const int m0 = blockIdx.y * 64;
  const float* W; const float* bias; int noff, ldw;
  if (n0 < 768)       { W = Wq;  bias = bq;  noff = n0;        ldw = 768; }
  else if (n0 < 1536) { W = Wk;  bias = bk;  noff = n0 - 768;  ldw = 768; }
  else if (n0 < 2304) { W = Wv;  bias = bv;  noff = n0 - 1536; ldw = 768; }
  else                { W = Wpv; bias = bpv; noff = n0 - 2304; ldw = 64; }
  __shared__ __bf16 As[64 * 72];   // [m][k] stride 72
  __shared__ __bf16 Bs[64 * 72];   // [n][k] stride 72 (transposed W)
  const int tid = threadIdx.x;
  const int lane = tid & 63;
  const int wv = tid >> 6;
  const int mh = wv & 1, nh = wv >> 1;
  const int ml5 = lane & 31, kq = lane >> 5;
  f32x16 acc;
#pragma unroll
  for (int z = 0; z < 16; z++) acc[z] = 0.f;

  for (int kc = 0; kc < 12; kc++) {
    // stage A: 64 rows x 64 k (float2 -> 2 bf16)
#pragma unroll
    for (int p = 0; p < 8; p++) {
      int e = p * 256 + tid;
      int row = e >> 5, c2 = e & 31;
      float2 v = *(const float2*)(hs + (m0 + row) * 768 + kc * 64 + c2 * 2);
      union { __bf16 h[2]; unsigned u; } pk;
      pk.h[0] = (__bf16)v.x; pk.h[1] = (__bf16)v.y;
      *(unsigned*)(As + row * 72 + c2 * 2) = pk.u;
    }
    // stage B transposed: W[k][n] -> Bs[n][k]
#pragma unroll
    for (int p = 0; p < 16; p++) {
      int e = p * 256 + tid;
      int kk = e >> 6, n = e & 63;
      Bs[n * 72 + kk] = (__bf16)W[(size_t)(kc * 64 + kk) * ldw + noff + n];
    }
    __syncthreads();
#pragma unroll
    for (int ks = 0; ks < 4; ks++) {
      bf16x8 af = *(const bf16x8*)(As + (mh * 32 + ml5) * 72 + ks * 16 + kq * 8);
      bf16x8 bf = *(const bf16x8*)(Bs + (nh * 32 + ml5) * 72 + ks * 16 + kq * 8);
      acc = __builtin_amdgcn_mfma_f32_32x32x16_bf16(af, bf, acc, 0, 0, 0);
    }
    __syncthreads();
  }
#pragma unroll
  for (int reg = 0; reg < 16; reg++) {
    int mrow = (reg & 3) + ((reg >> 2) << 3) + (kq << 2);
    int gm = m0 + mh * 32 + mrow;
    int nn = nh * 32 + ml5;
    qkv[(size_t)gm * 2368 + n0 + nn] = acc[reg] + bias[noff + nn];
  }
}

// ---------------- kernel T: Wip fp32 [768][1536] -> fragment-native bf16 ----------------
__global__ __launch_bounds__(256)
void wip_frag_kernel(const float* __restrict__ Wip, __bf16* __restrict__ wf) {
  __shared__ float lds_w[64 * 132];
  const int c = blockIdx.x;    // 0..11
  const int kc = blockIdx.y;   // 0..11
  const int tid = threadIdx.x;
  for (int e = tid; e < 8192; e += 256) {
    int row = e >> 7, col = e & 127;
    int gcol = ((col >> 6) * 768) + c * 64 + (col & 63);
    lds_w[row * 132 + col] = Wip[(size_t)(kc * 64 + row) * 1536 + gcol];
  }
  __syncthreads();
  for (int s = tid; s < 1024; s += 256) {
    int f = s >> 6, l = s & 63;
    int ks = f >> 2, half = (f >> 1) & 1, nt = f & 1;
    int col_local = half * 64 + nt * 32 + (l & 31);
    int kb = ks * 16 + (l >> 5) * 8;
    union { __bf16 h[8]; uint4 u; } pk;
#pragma unroll
    for (int j = 0; j < 8; j++)
      pk.h[j] = (__bf16)lds_w[(kb + j) * 132 + col_local];
    ((uint4*)wf)[(size_t)((c * 12 + kc) * 16 + f) * 64 + l] = pk.u;
  }
}

// ---------------- kernel B: fused ip-GEMM + score reduction ----------------
extern __shared__ char smem_raw[];

__global__ __launch_bounds__(512, 2)
void score_kernel(const float* __restrict__ infp,
                  const __bf16* __restrict__ wf,
                  const float* __restrict__ qkv,
                  float* __restrict__ scores) {
  char* Abase = smem_raw;                        // 96 frags * 1040 = 99840 B
  float* lds_sc = (float*)(smem_raw + 99840);    // 64*12 floats = 3072 B
  const int tid = threadIdx.x;
  const int lane = tid & 63;
  const int ml = lane & 31;
  const int kh = lane >> 5;
  const int wv = tid >> 6;       // 0..7
  const int wc = wv & 3;
  const int wd = wv >> 2;
  const int blk = blockIdx.x;
  const int b = blk >> 8;
  const int r0 = (blk & 255) << 6;

  for (int z = tid; z < 768; z += 512) lds_sc[z] = 0.f;

  // ---- stage A: 64 rows x 768 fp32 -> bf16 frag-ordered LDS
  {
    const float4* A4 = (const float4*)(infp + (size_t)(b * 16384 + r0) * 768);
#pragma unroll
    for (int p = 0; p < 12; p++) {
      int idx = p * 512 + tid;
      int m = (int)(((unsigned)idx * 10923u) >> 20);   // idx/96
      int g = idx - m * 96;
      float4 v0 = A4[m * 192 + g * 2];
      float4 v1 = A4[m * 192 + g * 2 + 1];
      union { __bf16 h[8]; uint4 u; } pk;
      pk.h[0] = (__bf16)v0.x; pk.h[1] = (__bf16)v0.y;
      pk.h[2] = (__bf16)v0.z; pk.h[3] = (__bf16)v0.w;
      pk.h[4] = (__bf16)v1.x; pk.h[5] = (__bf16)v1.y;
      pk.h[6] = (__bf16)v1.z; pk.h[7] = (__bf16)v1.w;
      int F = (m >> 5) * 48 + (g >> 1);
      int slot = (m & 31) + ((g & 1) << 5);
      *(uint4*)(Abase + ((F * 65 + slot) << 4)) = pk.u;
    }
  }
  __syncthreads();

  const size_t lane_off = (size_t)(lane << 4);
  uint4 Bcur[8], Bnxt[8];
  auto loadB = [&](uint4* dst, int c, int kc) {
    const char* base = (const char*)wf + (size_t)((c * 12 + kc) << 14) + (wd << 10) + lane_off;
#pragma unroll
    for (int ks = 0; ks < 4; ks++) {
      dst[ks * 2]     = *(const uint4*)(base + ks * 4096);          // ra
      dst[ks * 2 + 1] = *(const uint4*)(base + ks * 4096 + 2048);   // rb
    }
  };

  int c = wc;
  loadB(Bcur, c, 0);
  f32x16 acc_ra[2], acc_rb[2];
#pragma unroll
  for (int mt = 0; mt < 2; mt++)
#pragma unroll
    for (int z = 0; z < 16; z++) { acc_ra[mt][z] = 0.f; acc_rb[mt][z] = 0.f; }

  for (int it = 0; it < 36; it++) {
    int kc = it - (it >= 12 ? (it >= 24 ? 24 : 12) : 0);
    if (it < 35) {
      int nit = it + 1;
      int nkc = nit - (nit >= 12 ? (nit >= 24 ? 24 : 12) : 0);
      int nc = wc + (nit / 12) * 4;
      loadB(Bnxt, nc, nkc);
    }
    bf16x8 af[2][4];
#pragma unroll
    for (int mt = 0; mt < 2; mt++)
#pragma unroll
      for (int ks = 0; ks < 4; ks++)
        af[mt][ks] = *(const bf16x8*)(Abase + (((mt * 48 + kc * 4 + ks) * 65) << 4) + lane_off);
#pragma unroll
    for (int ks = 0; ks < 4; ks++) {
      bf16x8 bra = *(const bf16x8*)&Bcur[ks * 2];
      bf16x8 brb = *(const bf16x8*)&Bcur[ks * 2 + 1];
#pragma unroll
      for (int mt = 0; mt < 2; mt++) {
        acc_ra[mt] = __builtin_amdgcn_mfma_f32_32x32x16_bf16(af[mt][ks], bra, acc_ra[mt], 0, 0, 0);
        acc_rb[mt] = __builtin_amdgcn_mfma_f32_32x32x16_bf16(af[mt][ks], brb, acc_rb[mt], 0, 0, 0);
      }
    }
#pragma unroll
    for (int z = 0; z < 8; z++) Bcur[z] = Bnxt[z];

    if (kc == 11) {
      // ---- epilogue: batch ALL q/k loads first (one latency exposure), then reduce
      int d = wd * 32 + ml;
#pragma unroll
      for (int mt = 0; mt < 2; mt++) {
        float qv[16], kv[16];
#pragma unroll
        for (int reg = 0; reg < 16; reg++) {
          int row = mt * 32 + (reg & 3) + ((reg >> 2) << 3) + (kh << 2);
          int t = 12 * (r0 + row) + c;
          int hh = t >> 14;
          int ii = (t >> 7) & 127;
          int jj = t & 127;
          qv[reg] = qkv[(size_t)((b << 7) + ii) * 2368 + (hh << 6) + d];
          kv[reg] = qkv[(size_t)((b << 7) + jj) * 2368 + 768 + (hh << 6) + d];
        }
#pragma unroll
        for (int reg = 0; reg < 16; reg++) {
          int row = mt * 32 + (reg & 3) + ((reg >> 2) << 3) + (kh << 2);
          float p = (qv[reg] + acc_ra[mt][reg]) * (kv[reg] + acc_rb[mt][reg]);
          p += __shfl_xor(p, 16);
          p += __shfl_xor(p, 8);
          p += __shfl_xor(p, 4);
          p += __shfl_xor(p, 2);
          p += __shfl_xor(p, 1);
          if (ml == 0) atomicAdd(&lds_sc[row * 12 + c], p);
        }
      }
      c += 4;
#pragma unroll
      for (int mt = 0; mt < 2; mt++)
#pragma unroll
        for (int z = 0; z < 16; z++) { acc_ra[mt][z] = 0.f; acc_rb[mt][z] = 0.f; }
    }
  }

  __syncthreads();
  for (int z = tid; z < 768; z += 512) {
    int row = z / 12;
    int cc = z - row * 12;
    int t = 12 * (r0 + row) + cc;
    int hh = t >> 14;
    int ii = (t >> 7) & 127;
    int jj = t & 127;
    scores[(size_t)((b * 12 + hh) * 128 + ii) * 128 + jj] = lds_sc[z];
  }
}

// ---------------- kernel C: softmax + probs@v, 16 rows per block, V in LDS ----------------
__global__ __launch_bounds__(256)
void attn_kernel(const float* __restrict__ scores, const float* __restrict__ qkv,
                 const float* __restrict__ mask, const float* __restrict__ span,
                 float* __restrict__ ctx) {
  const int h = blockIdx.x;    // 0..12 (12 = parse path)
  const int ig = blockIdx.y;   // 0..7 (16 i each)
  const int b = blockIdx.z;
  const int tid = threadIdx.x;
  __shared__ float vs[128 * 64];   // V tile [j][d]
  __shared__ float w[128];
  __shared__ float red4[4];
  __shared__ float part[256];
  const int voff = (h < 12) ? 1536 + h * 64 : 2304;
  for (int e = tid; e < 8192; e += 256) {
    int j = e >> 6, d = e & 63;
    vs[j * 64 + d] = qkv[(size_t)(b * 128 + j) * 2368 + voff + d];
  }
  __syncthreads();
  const int j = tid & 127;
  const int wvi = tid >> 6;        // wave index 0..3 (2,3 duplicate 0,1)
  const int d = tid & 63, q4 = tid >> 6;
  for (int iq = 0; iq < 16; iq++) {
    int i = ig * 16 + iq;
    if (h < 12) {
      float s = scores[(size_t)((b * 12 + h) * 128 + i) * 128 + j] * 0.125f
              + mask[b * 128 + j];
      float mx = s;
#pragma unroll
      for (int o = 32; o; o >>= 1) mx = fmaxf(mx, __shfl_xor(mx, o));
      if ((tid & 63) == 0) red4[wvi] = mx;
      __syncthreads();
      mx = fmaxf(red4[0], red4[1]);
      float e = __expf(s - mx);
      float sm = e;
#pragma unroll
      for (int o = 32; o; o >>= 1) sm += __shfl_xor(sm, o);
      __syncthreads();
      if ((tid & 63) == 0) red4[wvi] = sm;
      __syncthreads();
      sm = red4[0] + red4[1];
      if (tid < 128) w[tid] = e / sm;
    } else {
      if (tid < 128) w[tid] = span[(size_t)(b * 128 + i) * 128 + j];
      __syncthreads();
      __syncthreads();
    }
    __syncthreads();
    float acc = 0.f;
#pragma unroll
    for (int jj = 0; jj < 32; jj++)
      acc += w[q4 * 32 + jj] * vs[(q4 * 32 + jj) * 64 + d];
    part[tid] = acc;
    __syncthreads();
    if (tid < 64)
      ctx[(size_t)(b * 128 + i) * 832 + h * 64 + tid] =
          part[tid] + part[tid + 64] + part[tid + 128] + part[tid + 192];
    __syncthreads();
  }
}

// ---------------- kernel D: out = ctx[256x832] @ Wmlp[832x768] + bmlp (bf16 MFMA) ----------------
__global__ __launch_bounds__(256)
void out_kernel(const float* __restrict__ ctxb, const float* __restrict__ Wmlp,
                const float* __restrict__ bmlp, float* __restrict__ out) {
  const int n0 = blockIdx.x * 64;   // 12 tiles
  const int m0 = blockIdx.y * 64;   // 4 tiles
  __shared__ __bf16 As[64 * 72];
  __shared__ __bf16 Bs[64 * 72];
  const int tid = threadIdx.x;
  const int lane = tid & 63;
  const int wv = tid >> 6;
  const int mh = wv & 1, nh = wv >> 1;
  const int ml5 = lane & 31, kq = lane >> 5;
  f32x16 acc;
#pragma unroll
  for (int z = 0; z < 16; z++) acc[z] = 0.f;

  for (int kc = 0; kc < 13; kc++) {
#pragma unroll
    for (int p = 0; p < 8; p++) {
      int e = p * 256 + tid;
      int row = e >> 5, c2 = e & 31;
      float2 v = *(const float2*)(ctxb + (size_t)(m0 + row) * 832 + kc * 64 + c2 * 2);
      union { __bf16 h[2]; unsigned u; } pk;
      pk.h[0] = (__bf16)v.x; pk.h[1] = (__bf16)v.y;
      *(unsigned*)(As + row * 72 + c2 * 2) = pk.u;
    }
#pragma unroll
    for (int p = 0; p < 16; p++) {
      int e = p * 256 + tid;
      int kk = e >> 6, n = e & 63;
      Bs[n * 72 + kk] = (__bf16)Wmlp[(size_t)(kc * 64 + kk) * 768 + n0 + n];
    }
    __syncthreads();
#pragma unroll
    for (int ks = 0; ks < 4; ks++) {
      bf16x8 af = *(const bf16x8*)(As + (mh * 32 + ml5) * 72 + ks * 16 + kq * 8);
      bf16x8 bf = *(const bf16x8*)(Bs + (nh * 32 + ml5) * 72 + ks * 16 + kq * 8);
      acc = __builtin_amdgcn_mfma_f32_32x32x16_bf16(af, bf, acc, 0, 0, 0);
    }
    __syncthreads();
  }
#pragma unroll
  for (int reg = 0; reg < 16; reg++) {
    int mrow = (reg & 3) + ((reg >> 2) << 3) + (kq << 2);
    int gm = m0 + mh * 32 + mrow;
    int nn = nh * 32 + ml5;
    out[(size_t)gm * 768 + n0 + nn] = acc[reg] + bmlp[n0 + nn];
  }
}

// ---------------- launch ----------------
extern "C" void kernel_launch(void* const* d_in, const int* in_sizes, int n_in,
                              void* d_out, int out_size, void* d_ws, size_t ws_size,
                              hipStream_t stream) {
  const float* hs   = (const float*)d_in[0];
  const float* mask = (const float*)d_in[1];
  const float* infp = (const float*)d_in[2];
  const float* span = (const float*)d_in[3];
  const float* Wq   = (const float*)d_in[4];
  const float* bq   = (const float*)d_in[5];
  const float* Wk   = (const float*)d_in[6];
  const float* bk   = (const float*)d_in[7];
  const float* Wv   = (const float*)d_in[8];
  const float* bv   = (const float*)d_in[9];
  const float* Wpv  = (const float*)d_in[10];
  const float* bpv  = (const float*)d_in[11];
  const float* Wip  = (const float*)d_in[12];
  const float* Wmlp = (const float*)d_in[13];
  const float* bmlp = (const float*)d_in[14];
  float* out = (float*)d_out;

  char* ws = (char*)d_ws;
  float*  qkv    = (float*)(ws);                 // 256*2368*4   = 2424832
  __bf16* wfrag  = (__bf16*)(ws + 2424832);      // 12*12*16*1024 = 2359296
  float*  scores = (float*)(ws + 4784128);       // 2*12*128*128*4 = 1572864
  float*  ctx    = (float*)(ws + 6356992);       // 256*832*4    = 851968
  // total ws usage: 7208960 bytes

  proj_kernel<<<dim3(37, 4), 256, 0, stream>>>(hs, Wq, bq, Wk, bk, Wv, bv, Wpv, bpv, qkv);
  wip_frag_kernel<<<dim3(12, 12), 256, 0, stream>>>(Wip, wfrag);
  score_kernel<<<dim3(512), 512, 102912, stream>>>(infp, wfrag, qkv, scores);
  attn_kernel<<<dim3(13, 8, 2), 256, 0, stream>>>(scores, qkv, mask, span, ctx);
  out_kernel<<<dim3(12, 4), 256, 0, stream>>>(ctx, Wmlp, bmlp, out);
}